// Round 2
// 644.021 us; speedup vs baseline: 1.0174x; 1.0174x over previous
//
#include <hip/hip_runtime.h>

// Problem constants (from reference)
constexpr int E = 64, I = 512, O = 512, T = 131072, CAP = 3072;

// GEMM tiling
constexpr int BM = 128, BN = 128, BK = 32;
constexpr int MT = CAP / BM;   // 24 m-tiles per expert (capacity-bounded)
constexpr int NT = O / BN;     // 4 n-tiles
constexpr int NK = I / BK;     // 16 k-iters

typedef __bf16 bf16x8 __attribute__((ext_vector_type(8)));
typedef float floatx4 __attribute__((ext_vector_type(4)));

// Pack two fp32 -> two bf16 (round via +0x8000, take high halves with v_perm)
__device__ inline unsigned pack_bf16(float a, float b) {
  unsigned ua = __float_as_uint(a) + 0x8000u;
  unsigned ub = __float_as_uint(b) + 0x8000u;
  return __builtin_amdgcn_perm(ub, ua, 0x07060302);
}

// Async global->LDS, 16B per lane. LDS dest is wave-uniform base + lane*16 (HW).
#define GLL16(g, s)                                                        \
  __builtin_amdgcn_global_load_lds(                                        \
      (const __attribute__((address_space(1))) unsigned int*)(g),          \
      (__attribute__((address_space(3))) unsigned int*)(s), 16, 0, 0)

// ---------------------------------------------------------------------------
// Kernel 1: bucket tokens by expert. counts padded to one 64B line each.
// ---------------------------------------------------------------------------
__global__ void scatter_k(const int* __restrict__ ids, int* __restrict__ counts,
                          int* __restrict__ bucket, float* __restrict__ out) {
  int t = blockIdx.x * blockDim.x + threadIdx.x;
  if (t >= T) return;
  int e = ids[t];
  int pos = atomicAdd(&counts[e * 16], 1);
  if (pos < CAP) {
    bucket[e * CAP + pos] = t;
  } else {
    float4 z = make_float4(0.f, 0.f, 0.f, 0.f);
    float* op = out + (size_t)t * O;
    for (int i = 0; i < O; i += 4) *(float4*)(op + i) = z;
  }
}

// ---------------------------------------------------------------------------
// Kernel 1b: convert weights fp32 -> bf16 (layout preserved [E][O][I]).
// ---------------------------------------------------------------------------
__global__ void convw_k(const float4* __restrict__ w, uint2* __restrict__ wb) {
  int i = blockIdx.x * blockDim.x + threadIdx.x;
  float4 f = w[i];
  wb[i] = make_uint2(pack_bf16(f.x, f.y), pack_bf16(f.z, f.w));
}

// ---------------------------------------------------------------------------
// Kernel 2: grouped GEMM. global_load_lds double-buffered staging,
// source-side XOR swizzle, 1 barrier per K-step, XCD-grouped bid decode.
// WBF=true: B staged as pre-converted bf16; false: B staged fp32 (fallback).
// ---------------------------------------------------------------------------
template <bool WBF>
__global__ __launch_bounds__(256, 3) void moe_gemm(
    const float* __restrict__ x, const float* __restrict__ w,
    const __bf16* __restrict__ wb, const float* __restrict__ bias,
    const int* __restrict__ counts, const int* __restrict__ bucket,
    float* __restrict__ out) {
  // XCD-grouped decode: the 4 nt-blocks of one (e,mt) share bid%8 -> same XCD
  const int bid = blockIdx.x;
  const int xcd = bid & 7;
  const int q8 = bid >> 3;
  const int nt = q8 & 3;
  const int G = (q8 >> 2) * 8 + xcd;  // 0..E*MT-1
  const int e = G / MT;
  const int mt = G - e * MT;

  int cnt = counts[e * 16];
  if (cnt < 0) cnt = 0;
  if (cnt > CAP) cnt = CAP;
  if (mt * BM >= cnt) return;  // empty m-tile (uniform across block -> safe)

  __shared__ __align__(16) float As[2][BM * BK];                  // 2x16KB
  __shared__ __align__(16) char BsRaw[2][BM * BK * (WBF ? 2 : 4)];
  __shared__ int toks[BM];

  const int t = threadIdx.x;
  const int lane = t & 63;
  const int wv = t >> 6;

  if (t < BM) {
    int g = mt * BM + t;
    toks[t] = (g < cnt) ? bucket[e * CAP + g] : -1;
  }
  __syncthreads();

  // A staging sources: wave wv round j covers rows [j*32+wv*8, +8), 8 quads/row.
  // Source quad pre-swizzled (sq = q ^ (row&7)) so linear LDS dest == swizzled
  // tile (rule: gload_lds dest must be linear; swizzle lives on src + read).
  const float* asrc[4];
#pragma unroll
  for (int j = 0; j < 4; ++j) {
    int row = j * 32 + wv * 8 + (lane >> 3);
    int tk = toks[row];
    if (tk < 0) tk = 0;  // safe dummy row; its output is discarded
    int sq = (lane & 7) ^ (row & 7);
    asrc[j] = x + (size_t)tk * I + sq * 4;
  }

  const __bf16* bsrcb[2];
  const float* bsrcf[4];
  if constexpr (WBF) {
    // bf16 B: round j covers rows [j*64+wv*16, +16), 4 quads/row (16B = 8 bf16)
#pragma unroll
    for (int j = 0; j < 2; ++j) {
      int row = j * 64 + wv * 16 + (lane >> 2);
      int sq = (lane & 3) ^ (row & 3);
      bsrcb[j] = wb + (size_t)(e * O + nt * BN + row) * I + sq * 8;
    }
  } else {
#pragma unroll
    for (int j = 0; j < 4; ++j) {
      int row = j * 32 + wv * 8 + (lane >> 3);
      int sq = (lane & 7) ^ (row & 7);
      bsrcf[j] = w + (size_t)(e * O + nt * BN + row) * I + sq * 4;
    }
  }

  auto stage = [&](int buf, int kk) {
#pragma unroll
    for (int j = 0; j < 4; ++j)
      GLL16(asrc[j] + kk * BK, &As[buf][(j * 32 + wv * 8) * BK]);
    if constexpr (WBF) {
      __bf16* Bs = (__bf16*)BsRaw[buf];
#pragma unroll
      for (int j = 0; j < 2; ++j)
        GLL16(bsrcb[j] + kk * BK, &Bs[(j * 64 + wv * 16) * BK]);
    } else {
      float* Bs = (float*)BsRaw[buf];
#pragma unroll
      for (int j = 0; j < 4; ++j)
        GLL16(bsrcf[j] + kk * BK, &Bs[(j * 32 + wv * 8) * BK]);
    }
  };

  const int wm = wv >> 1, wn = wv & 1;  // 2x2 wave grid, 64x64 each
  const int lrow = lane & 15;
  const int qd = lane >> 4;  // k-quarter 0..3

  floatx4 acc[4][4] = {};

  stage(0, 0);
  __syncthreads();  // compiler drains vmcnt(0) before barrier: buf0 ready

#pragma unroll
  for (int kk = 0; kk < NK; ++kk) {
    const int cur = kk & 1;
    if (kk + 1 < NK) stage(cur ^ 1, kk + 1);  // async loads fly during compute

    bf16x8 af[4], bfr[4];
#pragma unroll
    for (int mmi = 0; mmi < 4; ++mmi) {
      const int row = wm * 64 + mmi * 16 + lrow;
      const int s = row & 7;
      const float4 c0 =
          *(const float4*)&As[cur][row * BK + (((2 * qd) ^ s) << 2)];
      const float4 c1 =
          *(const float4*)&As[cur][row * BK + (((2 * qd + 1) ^ s) << 2)];
      bf16x8 a;
      a[0] = (__bf16)c0.x; a[1] = (__bf16)c0.y;
      a[2] = (__bf16)c0.z; a[3] = (__bf16)c0.w;
      a[4] = (__bf16)c1.x; a[5] = (__bf16)c1.y;
      a[6] = (__bf16)c1.z; a[7] = (__bf16)c1.w;
      af[mmi] = a;
    }
    if constexpr (WBF) {
      const __bf16* Bs = (const __bf16*)BsRaw[cur];
#pragma unroll
      for (int nni = 0; nni < 4; ++nni) {
        const int row = wn * 64 + nni * 16 + lrow;
        bfr[nni] = *(const bf16x8*)&Bs[row * BK + ((qd ^ (row & 3)) << 3)];
      }
    } else {
      const float* Bs = (const float*)BsRaw[cur];
#pragma unroll
      for (int nni = 0; nni < 4; ++nni) {
        const int row = wn * 64 + nni * 16 + lrow;
        const int s = row & 7;
        const float4 c0 =
            *(const float4*)&Bs[row * BK + (((2 * qd) ^ s) << 2)];
        const float4 c1 =
            *(const float4*)&Bs[row * BK + (((2 * qd + 1) ^ s) << 2)];
        bf16x8 b;
        b[0] = (__bf16)c0.x; b[1] = (__bf16)c0.y;
        b[2] = (__bf16)c0.z; b[3] = (__bf16)c0.w;
        b[4] = (__bf16)c1.x; b[5] = (__bf16)c1.y;
        b[6] = (__bf16)c1.z; b[7] = (__bf16)c1.w;
        bfr[nni] = b;
      }
    }

#pragma unroll
    for (int mmi = 0; mmi < 4; ++mmi)
#pragma unroll
      for (int nni = 0; nni < 4; ++nni)
        acc[mmi][nni] = __builtin_amdgcn_mfma_f32_16x16x32_bf16(
            af[mmi], bfr[nni], acc[mmi][nni], 0, 0, 0);

    __syncthreads();  // reads of cur done; stage writes of cur^1 landed
  }

  // Epilogue: add bias, scatter rows back to out[token].
  float bb[4];
#pragma unroll
  for (int nni = 0; nni < 4; ++nni)
    bb[nni] = bias[e * O + nt * BN + wn * 64 + nni * 16 + lrow];

  const int colbase = nt * BN + wn * 64 + lrow;
#pragma unroll
  for (int mmi = 0; mmi < 4; ++mmi) {
    const int rl = wm * 64 + mmi * 16 + qd * 4;
#pragma unroll
    for (int i = 0; i < 4; ++i) {
      const int tk = toks[rl + i];
      if (tk >= 0) {
        float* op = out + (size_t)tk * O + colbase;
#pragma unroll
        for (int nni = 0; nni < 4; ++nni)
          op[nni * 16] = acc[mmi][nni][i] + bb[nni];
      }
    }
  }
}

extern "C" void kernel_launch(void* const* d_in, const int* in_sizes, int n_in,
                              void* d_out, int out_size, void* d_ws,
                              size_t ws_size, hipStream_t stream) {
  const float* x = (const float*)d_in[0];
  const float* w = (const float*)d_in[1];
  const float* bias = (const float*)d_in[2];
  const int* ids = (const int*)d_in[3];
  float* out = (float*)d_out;

  // Workspace: [counts 64x16 ints | bucket E*CAP ints | wb E*O*I bf16]
  int* counts = (int*)d_ws;
  int* bucket = counts + 16 * E;
  __bf16* wbuf = (__bf16*)(bucket + E * CAP);
  const size_t need =
      (size_t)(16 * E + E * CAP) * sizeof(int) + (size_t)E * O * I * 2;

  hipMemsetAsync(counts, 0, 16 * E * sizeof(int), stream);
  scatter_k<<<dim3(T / 256), dim3(256), 0, stream>>>(ids, counts, bucket, out);

  if (ws_size >= need) {
    convw_k<<<dim3(E * O * I / 4 / 256), dim3(256), 0, stream>>>(
        (const float4*)w, (uint2*)wbuf);
    moe_gemm<true><<<dim3(E * MT * NT), dim3(256), 0, stream>>>(
        x, w, wbuf, bias, counts, bucket, out);
  } else {
    moe_gemm<false><<<dim3(E * MT * NT), dim3(256), 0, stream>>>(
        x, w, nullptr, bias, counts, bucket, out);
  }
}